// Round 12
// baseline (4012.144 us; speedup 1.0000x reference)
//
#include <hip/hip_runtime.h>
#include <math.h>

// 2-layer LSTM, B=64, T=512, F=256, H=512, fp32 — persistent cooperative kernel.
// R12: attack the serial handshake chain. R11 (2458us PASSED): load-first was
// only +2.4% => limiter is the per-step chain store->drainbar->publish->poll->
// bar->load (4.79us/step vs ~2us compute), MfmaUtil 12.4/VALUBusy 14.5.
// Changes vs R11 (both protocol/value-preserving):
// (1) PER-WAVE PUBLISH, 3 barriers/step -> 2: tokens per (tile, epilogue
//     wave) = slots[bg][layer][tile][w:4]. Each epilogue wave w (0..3) does
//     s_waitcnt vmcnt(0) (its own h/out stores) then stores its token; the
//     old drain barrier is deleted. Readers require ALL 4 sub-tokens >= tgt
//     == old single-token condition. Reads-done certification moves to the
//     combine barrier: every wave's h-loads are consumed by MFMAs part-
//     written BEFORE it; publish is after it.
// (2) part stride 66 -> 68: read bank = 4(b_e+g)+16p+u3 -> every bank
//     exactly 2x (free); was 4-way (SQ_LDS_BANK_CONFLICT 1.34e8 ~= 9%/step).
// Waits (R11 semantics): L0 front = 128 L0 tokens >= s; L0 back (pre-B2) =
// 128 L1 tokens >= s-2 (h0-store WAR); L1 front = all 256 tokens >= s.
// Else identical to R11: 4bg x 32tu x 2 layers = 256 blocks; block = 16
// batches x 16 units (4 N-tiles); W hi+lo limbs in VGPRs (L0: 8 waves x 3
// chunks {x:wv | h:2wv,2wv+1}, L1: 8 waves x 4 {(wv&3)*4+c of Wih1|Whh1});
// LOAD-FIRST h reads; h0 ring depth 4, h1 depth 2. Precision: h & W hi+lo
// bf16, 3 MFMAs/chunk/tile, fp32 acc, c in registers. MFMA 16x16x32 bf16:
// A=h (lane&15=batch, quad*8+j=k), B=W (lane&15=gate col),
// C: row=quad*4+reg, col=lane&15.

#define TT 512
#define FF 256
#define HH 512
#define NB 256

typedef __attribute__((ext_vector_type(4)))  float f32x4;
typedef __attribute__((ext_vector_type(8)))  short short8;
typedef __attribute__((ext_vector_type(16))) short short16;

__device__ __forceinline__ float sigmoidf_(float v){ return 1.0f/(1.0f+__expf(-v)); }

__device__ __forceinline__ unsigned short f2bf(float f){          // RTNE fp32->bf16
    unsigned u = __float_as_uint(f);
    u += 0x7FFFu + ((u>>16)&1u);
    return (unsigned short)(u>>16);
}
__device__ __forceinline__ float bf2f(unsigned short h){ return __uint_as_float(((unsigned)h)<<16); }

__device__ __forceinline__ unsigned long long ld8coh(const unsigned* p){
    return __hip_atomic_load((const unsigned long long*)p, __ATOMIC_RELAXED, __HIP_MEMORY_SCOPE_AGENT);
}
__device__ __forceinline__ void st4coh(unsigned* p, unsigned v){
    __hip_atomic_store(p, v, __ATOMIC_RELAXED, __HIP_MEMORY_SCOPE_AGENT);
}
__device__ __forceinline__ void stslot(int* p, int v){
    __hip_atomic_store(p, v, __ATOMIC_RELAXED, __HIP_MEMORY_SCOPE_AGENT);
}

union HU { unsigned long long q[4]; short16 v; };
union SL { unsigned long long q; int i[2]; };

__device__ __forceinline__ void split8(const float* v, short8& h8, short8& l8){
#pragma unroll
    for (int j=0;j<8;++j){
        const unsigned short hh = f2bf(v[j]);
        h8[j] = (short)hh;
        l8[j] = (short)f2bf(v[j]-bf2f(hh));
    }
}

__device__ __forceinline__ void loadsplit(const float* p, short8& h8, short8& l8){
    float v[8];
#pragma unroll
    for (int j=0;j<8;++j) v[j]=p[j];
    split8(v, h8, l8);
}

#define MFMA(a,b,c) __builtin_amdgcn_mfma_f32_16x16x32_bf16((a),(b),(c),0,0,0)

struct SMem { float part[8][16][68]; };   // stride 68 => 2-way max (free), ~34 KB

template<int LAYER>
__device__ __forceinline__ void run(
    const float* __restrict__ x,
    const float* __restrict__ WA, const float* __restrict__ WB,
    const float* __restrict__ bi, const float* __restrict__ bh,
    unsigned* __restrict__ hp0, unsigned* __restrict__ hp1,
    float* __restrict__ out, int* __restrict__ slots,
    const int bg, const int tile_u, SMem* sm)
{
    const int tid  = threadIdx.x;
    const int lane = tid & 63;
    const int wv   = __builtin_amdgcn_readfirstlane(tid>>6);  // K-slice index
    const int nn   = lane & 15;           // gate col / A batch row within tile
    const int quad = lane >> 4;           // k-octet within chunk
    const int bglob= bg*16 + nn;          // this lane's global batch row

    // ---- one-time: BOTH W limbs as B-fragments in registers, UNIFORM roles ----
    // L0 slots: 0 = x chunk wv (Wih0); 1,2 = h chunks 2wv,2wv+1 (Whh0)
    // L1 slots: 0..3 = chunks (wv&3)*4+c of (wv<4 ? Wih1 : Whh1)
    constexpr int NC = (LAYER==0) ? 3 : 4;
    short8 wHi[4][NC], wLo[4][NC];
#pragma unroll
    for (int nt=0;nt<4;++nt){
        const int jg = ((nn>>2)<<9) + (tile_u<<4) + (nt<<2) + (nn&3);
        if (LAYER==0){
            const float* rA = WA + (size_t)jg*FF;
            const float* rB = WB + (size_t)jg*HH;
            loadsplit(rA + wv*32 + quad*8, wHi[nt][0], wLo[nt][0]);
#pragma unroll
            for (int c=0;c<2;++c)
                loadsplit(rB + (2*wv+c)*32 + quad*8, wHi[nt][1+c], wLo[nt][1+c]);
        } else {
            const float* rw = ((wv<4) ? WA : WB) + (size_t)jg*HH;
#pragma unroll
            for (int c=0;c<4;++c)
                loadsplit(rw + ((wv&3)*4+c)*32 + quad*8, wHi[nt][c], wLo[nt][c]);
        }
    }

    // ---- epilogue thread state: bias regs + register-resident c ----
    const int b_e = tid>>4, ul = tid&15;        // (batch-in-group, unit-in-block)
    const int u_e = (tile_u<<4) + ul;           // global hidden unit
    float br[4]={0.f,0.f,0.f,0.f}; float creg=0.f;
    if (tid<256){
#pragma unroll
        for (int g=0; g<4; ++g) br[g] = bi[(g<<9)+u_e] + bh[(g<<9)+u_e];
    }

    // slots: [bg:4][layer:2][tile:32][wave:4]
    int* const sb = slots + bg*256;                      // this bg's block
    int* const mytok = sb + LAYER*128 + tile_u*4 + wv;   // valid for wv<4
    const f32x4 Z = {0.f,0.f,0.f,0.f};

#define LOADH(U, OCT) { \
        const unsigned* p_ = src + ((size_t)((OCT))*64 + bglob)*8; \
        U.q[0]=ld8coh(p_);   U.q[1]=ld8coh(p_+2); \
        U.q[2]=ld8coh(p_+4); U.q[3]=ld8coh(p_+6); }

#define MATHH(U, SLOT) { \
        const short8 aH = __builtin_shufflevector(U.v,U.v,0,2,4,6,8,10,12,14); \
        const short8 aL = __builtin_shufflevector(U.v,U.v,1,3,5,7,9,11,13,15); \
        _Pragma("unroll") \
        for (int nt=0;nt<4;++nt){ \
            accH[nt]=MFMA(aH,wHi[nt][(SLOT)],accH[nt]); \
            accM[nt]=MFMA(aH,wLo[nt][(SLOT)],accM[nt]); \
            accM[nt]=MFMA(aL,wHi[nt][(SLOT)],accM[nt]); \
        } }

    for (int s=0; s<=TT; ++s){
        const bool active = LAYER ? (s>0) : (s<TT);
        const int t = LAYER ? (s-1) : s;
        f32x4 accH[4], accM[4];
#pragma unroll
        for (int nt=0;nt<4;++nt){ accH[nt]=Z; accM[nt]=Z; }

        // ---- pre-wait: layer0 x-GEMM, chunk wv (immutable input) ----
        if (LAYER==0 && active){
            const float* p = x + ((size_t)bglob*TT + t)*FF + wv*32 + quad*8;
            float v[8];
            const float4 a0 = *(const float4*)(p);
            const float4 a1 = *(const float4*)(p+4);
            v[0]=a0.x; v[1]=a0.y; v[2]=a0.z; v[3]=a0.w;
            v[4]=a1.x; v[5]=a1.y; v[6]=a1.z; v[7]=a1.w;
            short8 aH, aL; split8(v, aH, aL);
#pragma unroll
            for (int nt=0;nt<4;++nt){
                accH[nt]=MFMA(aH,wHi[nt][0],accH[nt]);
                accM[nt]=MFMA(aH,wLo[nt][0],accM[nt]);
                accM[nt]=MFMA(aL,wHi[nt][0],accM[nt]);
            }
        }

        // ---- FRONT wait ----
        // L0: 128 L0 sub-tokens >= s. L1: all 256 sub-tokens >= s.
        if (wv==0){
            if (LAYER==0){
                const int* sp = sb + 2*lane;                 // L0 half
                for(;;){
                    SL a; a.q = ld8coh((const unsigned*)sp);
                    if (__all((a.i[0]>=s)&(a.i[1]>=s))) break;
                    __builtin_amdgcn_s_sleep(1);
                }
            } else {
                const int* sp0 = sb + 2*lane;                // L0 half
                const int* sp1 = sb + 128 + 2*lane;          // L1 half
                for(;;){
                    SL a,b; a.q = ld8coh((const unsigned*)sp0);
                    b.q = ld8coh((const unsigned*)sp1);
                    if (__all((a.i[0]>=s)&(a.i[1]>=s)&(b.i[0]>=s)&(b.i[1]>=s))) break;
                    __builtin_amdgcn_s_sleep(1);
                }
            }
        }
        __syncthreads();                                     // B1

        if (active){
            if (LAYER==0){
                const unsigned* src = hp0 + ((s+3)&3)*32768;       // h0[s-1]
                HU u0,u1;                                          // LOAD-FIRST
                LOADH(u0,(2*wv+0)*4+quad);
                LOADH(u1,(2*wv+1)*4+quad);
                MATHH(u0,1); MATHH(u1,2);
            } else {
                const unsigned* src = (wv<4) ? hp0 + ((s+3)&3)*32768   // h0[s-1]
                                             : hp1 + (s&1)*32768;      // h1[s-2]
                HU u0,u1,u2,u3;                                    // LOAD-FIRST
                LOADH(u0,((wv&3)*4+0)*4+quad);
                LOADH(u1,((wv&3)*4+1)*4+quad);
                LOADH(u2,((wv&3)*4+2)*4+quad);
                LOADH(u3,((wv&3)*4+3)*4+quad);
                MATHH(u0,0); MATHH(u1,1); MATHH(u2,2); MATHH(u3,3);
            }

            // ---- part writes for 8-way K-combine ----
#pragma unroll
            for (int nt=0;nt<4;++nt)
#pragma unroll
                for (int r=0;r<4;++r)
                    sm->part[wv][quad*4+r][nt*16+nn] = accH[nt][r]+accM[nt][r];
        }

        // ---- BACK wait (L0 only): h0-store WAR vs L1's read of h0[s-4] ----
        if (LAYER==0 && wv==0){
            const int* sp2 = sb + 128 + 2*lane;              // L1 half
            for(;;){
                SL a; a.q = ld8coh((const unsigned*)sp2);
                if (__all((a.i[0]>=s-2)&(a.i[1]>=s-2))) break;
                __builtin_amdgcn_s_sleep(1);
            }
        }
        __syncthreads();                                     // B2

        if (active && tid<256){
            float pre[4];
#pragma unroll
            for (int g=0; g<4; ++g){
                const int col = ((ul>>2)<<4) + (g<<2) + (ul&3);
                float sum = br[g];
#pragma unroll
                for (int w=0;w<8;++w) sum += sm->part[w][b_e][col];
                pre[g]=sum;
            }
            const float iv = sigmoidf_(pre[0]);
            const float fv = sigmoidf_(pre[1]);
            const float gv = tanhf(pre[2]);
            const float ov = sigmoidf_(pre[3]);
            creg = fv*creg + iv*gv;                      // c in a register
            const float hn = ov * tanhf(creg);
            const unsigned short hh = f2bf(hn);
            const unsigned short hl = f2bf(hn - bf2f(hh));
            const unsigned pk = ((unsigned)hl<<16) | (unsigned)hh;
            const int bge = bg*16 + b_e;
            const int idx = ((u_e>>3)*64 + bge)*8 + (u_e&7);  // hA[koct][b][8] pairs
            if (LAYER==0) st4coh(hp0 + (s&3)*32768 + idx, pk);
            else {
                st4coh(hp1 + ((s+1)&1)*32768 + idx, pk);     // h1[s-1] -> slot (s-1)&1
                out[((size_t)bge*TT + t)*HH + u_e] = hn;     // fp32, plain cached
            }
        }

        // ---- PER-WAVE publish: in-wave store drain, then own token ----
        if (wv < 4){
            asm volatile("s_waitcnt vmcnt(0)" ::: "memory");
            if (lane==0) stslot(mytok, s+1);
        }
    }
#undef LOADH
#undef MATHH
}

__global__ void __launch_bounds__(512,1) lstm_persist(
    const float* __restrict__ x,
    const float* __restrict__ Wih0, const float* __restrict__ Whh0,
    const float* __restrict__ bi0,  const float* __restrict__ bh0,
    const float* __restrict__ Wih1, const float* __restrict__ Whh1,
    const float* __restrict__ bi1,  const float* __restrict__ bh1,
    unsigned* hp0, unsigned* hp1, float* out, int* slots)
{
    __shared__ SMem sm;
    const int layer = blockIdx.x>>7, lid = blockIdx.x&127;
    const int bg = lid>>5, tile_u = lid&31;
    if (layer==0) run<0>(x, Wih0, Whh0, bi0, bh0, hp0, hp1, out, slots, bg, tile_u, &sm);
    else          run<1>(x, Wih1, Whh1, bi1, bh1, hp0, hp1, out, slots, bg, tile_u, &sm);
}

extern "C" void kernel_launch(void* const* d_in, const int* in_sizes, int n_in,
                              void* d_out, int out_size, void* d_ws, size_t ws_size,
                              hipStream_t stream) {
    (void)in_sizes; (void)n_in; (void)out_size; (void)ws_size;
    const float* x    = (const float*)d_in[0];
    const float* Wih0 = (const float*)d_in[1];
    const float* Whh0 = (const float*)d_in[2];
    const float* bi0  = (const float*)d_in[3];
    const float* bh0  = (const float*)d_in[4];
    const float* Wih1 = (const float*)d_in[5];
    const float* Whh1 = (const float*)d_in[6];
    const float* bi1  = (const float*)d_in[7];
    const float* bh1  = (const float*)d_in[8];
    float* out = (float*)d_out;
    unsigned* ws = (unsigned*)d_ws;

    // ws (uints): hp0 ring[4][32768] | hp1 ring[2][32768] | slots[1024]
    unsigned* hp0 = ws;                   // 4 slots x 128KB
    unsigned* hp1 = ws + 4*32768;         // 2 slots x 128KB
    int* slots    = (int*)(ws + 6*32768); // [bg:4][layer:2][tile:32][wave:4]

    hipMemsetAsync(d_ws, 0, (6*32768 + 1024)*sizeof(unsigned), stream);

    void* args[] = {
        (void*)&x, (void*)&Wih0, (void*)&Whh0, (void*)&bi0, (void*)&bh0,
        (void*)&Wih1, (void*)&Whh1, (void*)&bi1, (void*)&bh1,
        (void*)&hp0, (void*)&hp1, (void*)&out, (void*)&slots
    };
    hipLaunchCooperativeKernel((const void*)lstm_persist, dim3(NB), dim3(512),
                               args, 0, stream);
}